// Round 9
// baseline (414.925 us; speedup 1.0000x reference)
//
#include <hip/hip_runtime.h>
#include <hip/hip_bf16.h>
#include <math.h>

// MP_Attention: B=8,S=1024,E=1024,H=8,hd=128, fp32 in/out, bf16 MFMA internals.
// R9: attn is BARRIER-FREE — K/V are L2-resident (256 KB per bh), so waves load
// MFMA fragments directly from global (no LDS staging, no lockstep). GEMMs back
// to single-buffered 32KB-LDS m97 structure (4 blocks/CU; dbuf was the m132
// occupancy regression). Epilogues keep coalesced LDS bounce.

typedef __attribute__((ext_vector_type(4))) float f32x4;
typedef __attribute__((ext_vector_type(16))) float f32x16;
typedef __attribute__((ext_vector_type(4))) short s16x4;
typedef __attribute__((ext_vector_type(8))) short s16x8;

__device__ __forceinline__ short f2bf(float f) {
  union { __hip_bfloat16 h; short s; } u;
  u.h = __float2bfloat16(f);
  return u.s;
}
__device__ __forceinline__ float bf2f(short s) {
  union { short s; __hip_bfloat16 h; } u;
  u.s = s;
  return __bfloat162float(u.h);
}
__device__ __forceinline__ f32x4 mfma16(s16x8 a, s16x8 b, f32x4 c) {
  return __builtin_amdgcn_mfma_f32_16x16x32_bf16(a, b, c, 0, 0, 0);
}
__device__ __forceinline__ f32x16 mfma32(s16x8 a, s16x8 b, f32x16 c) {
  return __builtin_amdgcn_mfma_f32_32x32x16_bf16(a, b, c, 0, 0, 0);
}

typedef __attribute__((address_space(1))) const unsigned int* as1_u32p;
typedef __attribute__((address_space(3))) unsigned int* as3_u32p;
__device__ __forceinline__ void g2l16(const short* g, short* l) {
  __builtin_amdgcn_global_load_lds((as1_u32p)g, (as3_u32p)l, 16, 0, 0);
}

// ---------------- fused prep: weight-norm | query->bf16 | bias*log2e->bf16 --
__global__ __launch_bounds__(256) void k_prep(const float* __restrict__ qw, const float* __restrict__ kw,
                                              const float* __restrict__ vw, const float* __restrict__ ow,
                                              const float* __restrict__ gain, const float* __restrict__ query,
                                              const float* __restrict__ bias, short* __restrict__ wn,
                                              short* __restrict__ xq, short* __restrict__ b2) {
  __shared__ float red[256];
  const int bid = blockIdx.x, tid = threadIdx.x;
  if (bid < 4096) {
    // weight norm: wn = w * g / (sqrt(1024)*eps + ||row||)
    const int mat = bid >> 10;
    const float* W = mat == 0 ? qw : mat == 1 ? kw : mat == 2 ? vw : ow;
    const float* src = W + (size_t)(bid & 1023) * 1024;
    f32x4 v = *(const f32x4*)&src[tid * 4];
    float s = v[0]*v[0] + v[1]*v[1] + v[2]*v[2] + v[3]*v[3];
    red[tid] = s; __syncthreads();
    for (int off = 128; off > 0; off >>= 1) {
      if (tid < off) red[tid] += red[tid + off];
      __syncthreads();
    }
    const float scale = gain[0] / (0.0032f + sqrtf(red[0]));
    s16x4 o;
    o[0] = f2bf(v[0]*scale); o[1] = f2bf(v[1]*scale);
    o[2] = f2bf(v[2]*scale); o[3] = f2bf(v[3]*scale);
    *(s16x4*)&wn[(size_t)bid * 1024 + tid * 4] = o;
  } else if (bid < 6144) {
    // query fp32 -> bf16 (2,097,152 f32x4 elems; 2048 blocks x4 stride)
    for (int i = (bid - 4096) * 256 + tid; i < 2097152; i += 524288) {
      f32x4 v = ((const f32x4*)query)[i];
      s16x4 o;
      o[0] = f2bf(v[0]); o[1] = f2bf(v[1]); o[2] = f2bf(v[2]); o[3] = f2bf(v[3]);
      ((s16x4*)xq)[i] = o;
    }
  } else {
    // bias * log2e -> bf16 (2,097,152 f32x4 elems; 2048 blocks x4 stride)
    const float L2E = 1.4426950408889634f;
    for (int i = (bid - 6144) * 256 + tid; i < 2097152; i += 524288) {
      f32x4 v = ((const f32x4*)bias)[i];
      s16x4 o;
      o[0] = f2bf(v[0]*L2E); o[1] = f2bf(v[1]*L2E);
      o[2] = f2bf(v[2]*L2E); o[3] = f2bf(v[3]*L2E);
      ((s16x4*)b2)[i] = o;
    }
  }
}

// ======== GEMM core: 128x128 tile, BK=64, SINGLE-buffered (m97 structure) ===
// LDS [128][64] shorts/operand (32 KB total -> 4 blocks/CU); 16B-slot swizzle
// slot^=(row&7) on pre-swizzled global source (write) and ds_read (read).
__device__ __forceinline__ void gemm_core(const short* __restrict__ X, const short* __restrict__ W_,
                                          int m0, int n0, int lane, int w, int hi, int ql,
                                          int wm, int wn_, short* Al, short* Bl,
                                          f32x4 acc[4][4]) {
  const int srw = lane >> 3, ssl = lane & 7, ql7 = ql & 7;
  for (int t = 0; t < 16; ++t) {
    const int k0 = t * 64;
#pragma unroll
    for (int i = 0; i < 4; i++) {
      const int row = i * 32 + w * 8 + srw;
      g2l16(&X[(size_t)(m0 + row) * 1024 + k0 + ((ssl ^ srw) << 3)],
            &Al[(i * 32 + w * 8) * 64]);
      g2l16(&W_[(size_t)(n0 + row) * 1024 + k0 + ((ssl ^ srw) << 3)],
            &Bl[(i * 32 + w * 8) * 64]);
    }
    __syncthreads();   // drains vmcnt (barrier semantics) -> LDS tile ready
    __builtin_amdgcn_s_setprio(1);
#pragma unroll
    for (int kc = 0; kc < 2; ++kc) {
      s16x8 af[4], bfr[4];
#pragma unroll
      for (int i = 0; i < 4; i++) {
        const int rA = wm * 64 + i * 16 + ql;
        af[i] = *(const s16x8*)((const char*)Al + rA * 128 + ((kc * 64 + 16 * hi) ^ (ql7 << 4)));
      }
#pragma unroll
      for (int j = 0; j < 4; j++) {
        const int rB = wn_ * 64 + j * 16 + ql;
        bfr[j] = *(const s16x8*)((const char*)Bl + rB * 128 + ((kc * 64 + 16 * hi) ^ (ql7 << 4)));
      }
#pragma unroll
      for (int i = 0; i < 4; i++)
#pragma unroll
        for (int j = 0; j < 4; j++) acc[i][j] = mfma16(af[i], bfr[j], acc[i][j]);
    }
    __builtin_amdgcn_s_setprio(0);
    __syncthreads();   // all waves done reading before next overwrite
  }
}

// ---------------- QKV GEMM: C = X * WN^T  (z=0:Q, 1:K, 2:V-transposed) ------
__global__ __launch_bounds__(256) void k_gemm_qkv(const short* __restrict__ X, const short* __restrict__ WN,
                                                  short* __restrict__ Qb, short* __restrict__ Kb,
                                                  short* __restrict__ Vt) {
  __shared__ short lds[16384];   // Al 16K | Bl 16K; epilogue reuses all 32 KB
  short* Al = lds;
  short* Bl = lds + 8192;
  const int z = blockIdx.z;
  const short* __restrict__ Wm = WN + (size_t)z * 1048576;
  const int m0 = blockIdx.x * 128, n0 = blockIdx.y * 128;
  const int tid = threadIdx.x, lane = tid & 63, w = tid >> 6;
  const int hi = lane >> 4, ql = lane & 15;
  const int wm = w >> 1, wn_ = w & 1;
  f32x4 acc[4][4];
#pragma unroll
  for (int i = 0; i < 4; i++)
#pragma unroll
    for (int j = 0; j < 4; j++) acc[i][j] = (f32x4){0.f, 0.f, 0.f, 0.f};
  gemm_core(X, Wm, m0, n0, lane, w, hi, ql, wm, wn_, Al, Bl, acc);
  // epilogue via LDS bounce (32 KB = 128x128 bf16) for coalesced writes
  short* Cl = lds;
  if (z == 2) {
    // store TRANSPOSED in LDS: Cl[ng_local][m_local]
#pragma unroll
    for (int i = 0; i < 4; i++) {
#pragma unroll
      for (int j = 0; j < 4; j++) {
        int col = wn_ * 64 + j * 16 + ql;
        int rowb = wm * 64 + i * 16 + 4 * hi;
#pragma unroll
        for (int r = 0; r < 4; r++) Cl[col * 128 + rowb + r] = f2bf(acc[i][j][r]);
      }
    }
    __syncthreads();
    const int b = m0 >> 10, sb = (m0 & 1023);
#pragma unroll
    for (int it = 0; it < 8; ++it) {
      int idx = tid + it * 256;
      int dl = idx >> 4, c = idx & 15;       // dl: 0..127 (n-local), c: 16B chunk
      int ng = n0 + dl, h = ng >> 7, d = ng & 127;
      *(s16x8*)&Vt[(size_t)((b * 8 + h) * 128 + d) * 1024 + sb + c * 8] =
          *(const s16x8*)&Cl[dl * 128 + c * 8];
    }
  } else {
    short* __restrict__ C = (z == 0) ? Qb : Kb;
#pragma unroll
    for (int i = 0; i < 4; i++) {
#pragma unroll
      for (int j = 0; j < 4; j++) {
        int col = wn_ * 64 + j * 16 + ql;
        int rowb = wm * 64 + i * 16 + 4 * hi;
#pragma unroll
        for (int r = 0; r < 4; r++) Cl[(rowb + r) * 128 + col] = f2bf(acc[i][j][r]);
      }
    }
    __syncthreads();
#pragma unroll
    for (int it = 0; it < 8; ++it) {
      int idx = tid + it * 256;
      int row = idx >> 4, c = idx & 15;
      *(s16x8*)&C[(size_t)(m0 + row) * 1024 + n0 + c * 8] = *(const s16x8*)&Cl[row * 128 + c * 8];
    }
  }
}

// ---------------- flash attention: BARRIER-FREE, direct-L2 fragments --------
// K/V per (b,h) = 256 KB each -> L2-resident (8 q-blocks share via XCD swizzle).
// Per wave: 32 q-rows; QK^T A-frag = 16B global load of K row; PV A-frag = two
// 8B loads of Vt row reproducing k-map kappa(hi2,e)=4*hi2+(e&3)+8*(e>>2), the
// SAME map used by the P-pack (verified vs R6/R8 passing layout). No LDS/bars
// in the loop; waves free-run and hide L2 latency by occupancy.
__global__ __launch_bounds__(256) void k_attn(const short* __restrict__ Qb, const short* __restrict__ Kb,
                                              const short* __restrict__ Vt, const short* __restrict__ B2,
                                              short* __restrict__ Ob) {
  __shared__ short lds[128 * 128];   // 32 KB, epilogue bounce only
  // XCD swizzle: nwg=512, 64/XCD -> 8 full bh per XCD (K/V L2 reuse)
  int f = blockIdx.x + (blockIdx.y << 3);
  f = (f & 7) * 64 + (f >> 3);
  const int bh = f >> 3, b = bh >> 3, h = bh & 7;
  const int q0 = (f & 7) * 128;
  const int tid = threadIdx.x, w = tid >> 6, lane = tid & 63;
  const int l31 = lane & 31, hi2 = lane >> 5;
  const int qrow = q0 + w * 32 + l31;
  const short* __restrict__ qbase = Qb + (size_t)(b * 1024 + qrow) * 1024 + h * 128;
  s16x8 qf[8];   // Q[qrow][kc*16 + hi2*8 + e]
#pragma unroll
  for (int kc = 0; kc < 8; kc++) qf[kc] = *(const s16x8*)&qbase[kc * 16 + hi2 * 8];
  float lsum = 0.f;
  f32x16 acc[4];
#pragma unroll
  for (int db = 0; db < 4; db++)
#pragma unroll
    for (int r = 0; r < 16; r++) acc[db][r] = 0.f;
  // scores bounded (|q.k|/sqrt(128) ~<15): exp2(st*sc2 + bias*log2e), no max.
  const float sc2 = (float)(0.08838834764831845 * 1.4426950408889634);
  const short* __restrict__ Kg = Kb + (size_t)(b * 1024) * 1024 + h * 128;
  const short* __restrict__ Vg = Vt + (size_t)bh * 128 * 1024;
  const short* __restrict__ Bg = B2 + (size_t)(h * 1024 + qrow) * 1024;

  for (int t0 = 0; t0 < 1024; t0 += 64) {
    // ---- S^T = K * Q^T : D[t][q], q = own l31, t = tb*32 + (r&3)+8*(r>>2)+4*hi2
    f32x16 st[2];
    __builtin_amdgcn_s_setprio(1);
#pragma unroll
    for (int tb = 0; tb < 2; tb++) {
#pragma unroll
      for (int r = 0; r < 16; r++) st[tb][r] = 0.f;
#pragma unroll
      for (int kc = 0; kc < 8; kc++) {
        s16x8 kf = *(const s16x8*)&Kg[(size_t)(t0 + tb * 32 + l31) * 1024 + kc * 16 + hi2 * 8];
        st[tb] = mfma32(kf, qf[kc], st[tb]);
      }
    }
    __builtin_amdgcn_s_setprio(0);
    // ---- bias + exp2 softmax (unnormalized, no max)
    s16x4 br[8];  // t = t0 + tb*32 + u*8 + 4*hi2 + j
#pragma unroll
    for (int tb = 0; tb < 2; tb++)
#pragma unroll
      for (int u = 0; u < 4; u++)
        br[tb * 4 + u] = *(const s16x4*)&Bg[t0 + tb * 32 + u * 8 + 4 * hi2];
#pragma unroll
    for (int tb = 0; tb < 2; tb++)
#pragma unroll
      for (int r = 0; r < 16; r++) {
        float e = exp2f(fmaf(st[tb][r], sc2, bf2f(br[tb * 4 + (r >> 2)][r & 3])));
        st[tb][r] = e;
        lsum += e;
      }
    // ---- pack P^T: pf[ks][e] = P[t = ks*16 + kappa(hi2,e)], lane-local
    s16x8 pf[4];
#pragma unroll
    for (int ks = 0; ks < 4; ks++)
#pragma unroll
      for (int e = 0; e < 8; e++)
        pf[ks][e] = f2bf(st[ks >> 1][(e & 3) + 8 * (ks & 1) + 4 * (e >> 2)]);
    // ---- O^T += V^T * P^T : A-frag direct from global with same kappa
    __builtin_amdgcn_s_setprio(1);
#pragma unroll
    for (int db = 0; db < 4; db++)
#pragma unroll
      for (int ks = 0; ks < 4; ks++) {
        const short* vp = &Vg[(size_t)(db * 32 + l31) * 1024 + t0 + ks * 16 + 4 * hi2];
        s16x4 lo  = *(const s16x4*)vp;        // t = ks*16 + 4*hi2 + {0..3}
        s16x4 hi4 = *(const s16x4*)(vp + 8);  // t = ks*16 + 8 + 4*hi2 + {0..3}
        s16x8 vf;
        vf[0] = lo[0]; vf[1] = lo[1]; vf[2] = lo[2]; vf[3] = lo[3];
        vf[4] = hi4[0]; vf[5] = hi4[1]; vf[6] = hi4[2]; vf[7] = hi4[3];
        acc[db] = mfma32(vf, pf[ks], acc[db]);
      }
    __builtin_amdgcn_s_setprio(0);
  }
  // reduce lsum (lanes 32 apart hold disjoint t-slices of same q)
  lsum += __shfl_xor(lsum, 32);
  const float invl = 1.f / lsum;
  // epilogue: O[q][d] via swizzled LDS bounce [128 q][128 d]
  short* Ol = lds;
  const int qloc = w * 32 + l31, qs = qloc & 7;
#pragma unroll
  for (int db = 0; db < 4; db++) {
#pragma unroll
    for (int u = 0; u < 4; u++) {
      int d0 = db * 32 + u * 8 + 4 * hi2;
      s16x4 v;
      v[0] = f2bf(acc[db][4 * u + 0] * invl);
      v[1] = f2bf(acc[db][4 * u + 1] * invl);
      v[2] = f2bf(acc[db][4 * u + 2] * invl);
      v[3] = f2bf(acc[db][4 * u + 3] * invl);
      *(s16x4*)((char*)Ol + qloc * 256 + (((d0 >> 3) ^ qs) << 4) + (d0 & 7) * 2) = v;
    }
  }
  __syncthreads();
#pragma unroll
  for (int it = 0; it < 8; ++it) {
    int idx = tid + it * 256;
    int row = idx >> 4, c = idx & 15;
    s16x8 vv = *(const s16x8*)((const char*)Ol + row * 256 + ((c ^ (row & 7)) << 4));
    *(s16x8*)&Ob[(size_t)(b * 1024 + q0 + row) * 1024 + h * 128 + c * 8] = vv;
  }
}

// ---------------- O-proj GEMM + fused mp_sum residual (fp32 out) ------------
__global__ __launch_bounds__(256) void k_gemm_o(const short* __restrict__ X, const short* __restrict__ Wm,
                                                const float* __restrict__ Qin, float* __restrict__ Out) {
  __shared__ short lds[16384];
  short* Al = lds;
  short* Bl = lds + 8192;
  const int m0 = blockIdx.x * 128, n0 = blockIdx.y * 128;
  const int tid = threadIdx.x, lane = tid & 63, w = tid >> 6;
  const int hi = lane >> 4, ql = lane & 15;
  const int wm = w >> 1, wn_ = w & 1;
  f32x4 acc[4][4];
#pragma unroll
  for (int i = 0; i < 4; i++)
#pragma unroll
    for (int j = 0; j < 4; j++) acc[i][j] = (f32x4){0.f, 0.f, 0.f, 0.f};
  gemm_core(X, Wm, m0, n0, lane, w, hi, ql, wm, wn_, Al, Bl, acc);
  // out = (query + o @ own^T) * 1/sqrt(2)   [t=0.5 mp_sum]
#pragma unroll
  for (int i = 0; i < 4; i++) {
    int mg = m0 + wm * 64 + i * 16 + 4 * hi;
#pragma unroll
    for (int j = 0; j < 4; j++) {
      int ng = n0 + wn_ * 64 + j * 16 + ql;
#pragma unroll
      for (int r = 0; r < 4; r++) {
        size_t idx = (size_t)(mg + r) * 1024 + ng;
        Out[idx] = (Qin[idx] + acc[i][j][r]) * 0.7071067811865476f;
      }
    }
  }
}

extern "C" void kernel_launch(void* const* d_in, const int* in_sizes, int n_in,
                              void* d_out, int out_size, void* d_ws, size_t ws_size,
                              hipStream_t stream) {
  (void)in_sizes; (void)n_in; (void)out_size; (void)ws_size;
  const float* query = (const float*)d_in[0];
  const float* gain_s = (const float*)d_in[1];
  // d_in[2] = gain_t (unused: time_dim=0)
  const float* qw = (const float*)d_in[3];
  const float* kw = (const float*)d_in[4];
  const float* vw = (const float*)d_in[5];
  const float* ow = (const float*)d_in[6];
  const float* bias = (const float*)d_in[7];
  float* out = (float*)d_out;

  // workspace (shorts): 4+8+8+8+8+8 = 44M shorts = 88 MB
  short* ws = (short*)d_ws;
  short* s_wn = ws;                       // 4 x 1M  (q,k,v,o normalized bf16)
  short* s_x  = s_wn + 4 * 1048576;       // 8M  query bf16; REUSED as attn output
  short* s_B2 = s_x + 8388608;            // 8M  bf16 bias * log2e
  short* s_Q  = s_B2 + 8388608;           // 8M
  short* s_K  = s_Q + 8388608;            // 8M
  short* s_Vt = s_K + 8388608;            // 8M  V transposed [b][h][d][s]
  short* s_O  = s_x;                      // alias: x dead after QKV GEMM

  k_prep<<<dim3(8192), dim3(256), 0, stream>>>(qw, kw, vw, ow, gain_s, query, bias, s_wn, s_x, s_B2);
  k_gemm_qkv<<<dim3(64, 8, 3), dim3(256), 0, stream>>>(s_x, s_wn, s_Q, s_K, s_Vt);
  k_attn<<<dim3(8, 64), dim3(256), 0, stream>>>(s_Q, s_K, s_Vt, s_B2, s_O);
  k_gemm_o<<<dim3(64, 8), dim3(256), 0, stream>>>(s_O, s_wn + 3 * 1048576, query, out);
}

// Round 10
// 318.734 us; speedup vs baseline: 1.3018x; 1.3018x over previous
//
#include <hip/hip_runtime.h>
#include <hip/hip_bf16.h>
#include <math.h>

// MP_Attention: B=8,S=1024,E=1024,H=8,hd=128, fp32 in/out, bf16 MFMA internals.
// R10: attn = R8's LDS-staged 32x32 kernel SPLIT over t (blockIdx.z halves):
// no-max softmax partials are additive, so each split writes unnormalized bf16
// O-partial + f32 lsum; k_merge combines. 1024 blocks (4/CU) halve the serial
// chain and double independent streams. GEMMs = R9 single-buffered m97.

typedef __attribute__((ext_vector_type(4))) float f32x4;
typedef __attribute__((ext_vector_type(16))) float f32x16;
typedef __attribute__((ext_vector_type(4))) short s16x4;
typedef __attribute__((ext_vector_type(8))) short s16x8;

__device__ __forceinline__ short f2bf(float f) {
  union { __hip_bfloat16 h; short s; } u;
  u.h = __float2bfloat16(f);
  return u.s;
}
__device__ __forceinline__ float bf2f(short s) {
  union { short s; __hip_bfloat16 h; } u;
  u.s = s;
  return __bfloat162float(u.h);
}
__device__ __forceinline__ f32x4 mfma16(s16x8 a, s16x8 b, f32x4 c) {
  return __builtin_amdgcn_mfma_f32_16x16x32_bf16(a, b, c, 0, 0, 0);
}
__device__ __forceinline__ f32x16 mfma32(s16x8 a, s16x8 b, f32x16 c) {
  return __builtin_amdgcn_mfma_f32_32x32x16_bf16(a, b, c, 0, 0, 0);
}

typedef __attribute__((address_space(1))) const unsigned int* as1_u32p;
typedef __attribute__((address_space(3))) unsigned int* as3_u32p;
__device__ __forceinline__ void g2l16(const short* g, short* l) {
  __builtin_amdgcn_global_load_lds((as1_u32p)g, (as3_u32p)l, 16, 0, 0);
}

#define ASM_VMCNT0 asm volatile("s_waitcnt vmcnt(0)" ::: "memory")
#define ASM_LGKM0  asm volatile("s_waitcnt lgkmcnt(0)" ::: "memory")
#define SFENCE     __builtin_amdgcn_sched_barrier(0)
#define BARRIER    __builtin_amdgcn_s_barrier()

// ---------------- fused prep: weight-norm | query->bf16 | bias*log2e->bf16 --
__global__ __launch_bounds__(256) void k_prep(const float* __restrict__ qw, const float* __restrict__ kw,
                                              const float* __restrict__ vw, const float* __restrict__ ow,
                                              const float* __restrict__ gain, const float* __restrict__ query,
                                              const float* __restrict__ bias, short* __restrict__ wn,
                                              short* __restrict__ xq, short* __restrict__ b2) {
  __shared__ float red[256];
  const int bid = blockIdx.x, tid = threadIdx.x;
  if (bid < 4096) {
    const int mat = bid >> 10;
    const float* W = mat == 0 ? qw : mat == 1 ? kw : mat == 2 ? vw : ow;
    const float* src = W + (size_t)(bid & 1023) * 1024;
    f32x4 v = *(const f32x4*)&src[tid * 4];
    float s = v[0]*v[0] + v[1]*v[1] + v[2]*v[2] + v[3]*v[3];
    red[tid] = s; __syncthreads();
    for (int off = 128; off > 0; off >>= 1) {
      if (tid < off) red[tid] += red[tid + off];
      __syncthreads();
    }
    const float scale = gain[0] / (0.0032f + sqrtf(red[0]));
    s16x4 o;
    o[0] = f2bf(v[0]*scale); o[1] = f2bf(v[1]*scale);
    o[2] = f2bf(v[2]*scale); o[3] = f2bf(v[3]*scale);
    *(s16x4*)&wn[(size_t)bid * 1024 + tid * 4] = o;
  } else if (bid < 6144) {
    for (int i = (bid - 4096) * 256 + tid; i < 2097152; i += 524288) {
      f32x4 v = ((const f32x4*)query)[i];
      s16x4 o;
      o[0] = f2bf(v[0]); o[1] = f2bf(v[1]); o[2] = f2bf(v[2]); o[3] = f2bf(v[3]);
      ((s16x4*)xq)[i] = o;
    }
  } else {
    const float L2E = 1.4426950408889634f;
    for (int i = (bid - 6144) * 256 + tid; i < 2097152; i += 524288) {
      f32x4 v = ((const f32x4*)bias)[i];
      s16x4 o;
      o[0] = f2bf(v[0]*L2E); o[1] = f2bf(v[1]*L2E);
      o[2] = f2bf(v[2]*L2E); o[3] = f2bf(v[3]*L2E);
      ((s16x4*)b2)[i] = o;
    }
  }
}

// ======== GEMM core: 128x128 tile, BK=64, single-buffered (m97, R9) =========
__device__ __forceinline__ void gemm_core(const short* __restrict__ X, const short* __restrict__ W_,
                                          int m0, int n0, int lane, int w, int hi, int ql,
                                          int wm, int wn_, short* Al, short* Bl,
                                          f32x4 acc[4][4]) {
  const int srw = lane >> 3, ssl = lane & 7, ql7 = ql & 7;
  for (int t = 0; t < 16; ++t) {
    const int k0 = t * 64;
#pragma unroll
    for (int i = 0; i < 4; i++) {
      const int row = i * 32 + w * 8 + srw;
      g2l16(&X[(size_t)(m0 + row) * 1024 + k0 + ((ssl ^ srw) << 3)],
            &Al[(i * 32 + w * 8) * 64]);
      g2l16(&W_[(size_t)(n0 + row) * 1024 + k0 + ((ssl ^ srw) << 3)],
            &Bl[(i * 32 + w * 8) * 64]);
    }
    __syncthreads();
    __builtin_amdgcn_s_setprio(1);
#pragma unroll
    for (int kc = 0; kc < 2; ++kc) {
      s16x8 af[4], bfr[4];
#pragma unroll
      for (int i = 0; i < 4; i++) {
        const int rA = wm * 64 + i * 16 + ql;
        af[i] = *(const s16x8*)((const char*)Al + rA * 128 + ((kc * 64 + 16 * hi) ^ (ql7 << 4)));
      }
#pragma unroll
      for (int j = 0; j < 4; j++) {
        const int rB = wn_ * 64 + j * 16 + ql;
        bfr[j] = *(const s16x8*)((const char*)Bl + rB * 128 + ((kc * 64 + 16 * hi) ^ (ql7 << 4)));
      }
#pragma unroll
      for (int i = 0; i < 4; i++)
#pragma unroll
        for (int j = 0; j < 4; j++) acc[i][j] = mfma16(af[i], bfr[j], acc[i][j]);
    }
    __builtin_amdgcn_s_setprio(0);
    __syncthreads();
  }
}

// ---------------- QKV GEMM: C = X * WN^T  (z=0:Q, 1:K, 2:V-transposed) ------
__global__ __launch_bounds__(256) void k_gemm_qkv(const short* __restrict__ X, const short* __restrict__ WN,
                                                  short* __restrict__ Qb, short* __restrict__ Kb,
                                                  short* __restrict__ Vt) {
  __shared__ short lds[16384];
  short* Al = lds;
  short* Bl = lds + 8192;
  const int z = blockIdx.z;
  const short* __restrict__ Wm = WN + (size_t)z * 1048576;
  const int m0 = blockIdx.x * 128, n0 = blockIdx.y * 128;
  const int tid = threadIdx.x, lane = tid & 63, w = tid >> 6;
  const int hi = lane >> 4, ql = lane & 15;
  const int wm = w >> 1, wn_ = w & 1;
  f32x4 acc[4][4];
#pragma unroll
  for (int i = 0; i < 4; i++)
#pragma unroll
    for (int j = 0; j < 4; j++) acc[i][j] = (f32x4){0.f, 0.f, 0.f, 0.f};
  gemm_core(X, Wm, m0, n0, lane, w, hi, ql, wm, wn_, Al, Bl, acc);
  short* Cl = lds;
  if (z == 2) {
#pragma unroll
    for (int i = 0; i < 4; i++) {
#pragma unroll
      for (int j = 0; j < 4; j++) {
        int col = wn_ * 64 + j * 16 + ql;
        int rowb = wm * 64 + i * 16 + 4 * hi;
#pragma unroll
        for (int r = 0; r < 4; r++) Cl[col * 128 + rowb + r] = f2bf(acc[i][j][r]);
      }
    }
    __syncthreads();
    const int b = m0 >> 10, sb = (m0 & 1023);
#pragma unroll
    for (int it = 0; it < 8; ++it) {
      int idx = tid + it * 256;
      int dl = idx >> 4, c = idx & 15;
      int ng = n0 + dl, h = ng >> 7, d = ng & 127;
      *(s16x8*)&Vt[(size_t)((b * 8 + h) * 128 + d) * 1024 + sb + c * 8] =
          *(const s16x8*)&Cl[dl * 128 + c * 8];
    }
  } else {
    short* __restrict__ C = (z == 0) ? Qb : Kb;
#pragma unroll
    for (int i = 0; i < 4; i++) {
#pragma unroll
      for (int j = 0; j < 4; j++) {
        int col = wn_ * 64 + j * 16 + ql;
        int rowb = wm * 64 + i * 16 + 4 * hi;
#pragma unroll
        for (int r = 0; r < 4; r++) Cl[(rowb + r) * 128 + col] = f2bf(acc[i][j][r]);
      }
    }
    __syncthreads();
#pragma unroll
    for (int it = 0; it < 8; ++it) {
      int idx = tid + it * 256;
      int row = idx >> 4, c = idx & 15;
      *(s16x8*)&C[(size_t)(m0 + row) * 1024 + n0 + c * 8] = *(const s16x8*)&Cl[row * 128 + c * 8];
    }
  }
}

// ---------------- flash attention, t-SPLIT (z=0: t<512, z=1: t>=512) --------
// R8 structure: LDS-staged K/V, 32x32 MFMA, 32 q/wave, raw-barrier pipeline.
// Writes UNNORMALIZED bf16 O-partial + f32 lsum; k_merge combines.
__global__ __launch_bounds__(256) void k_attn(const short* __restrict__ Qb, const short* __restrict__ Kb,
                                              const short* __restrict__ Vt, const short* __restrict__ B2,
                                              short* __restrict__ Op, float* __restrict__ Ls) {
  __shared__ short lds[64 * 128 + 128 * 64];   // 32 KB (K 16K + V 16K)
  short* Kl = lds;
  short* Vl = lds + 64 * 128;
  const int split = blockIdx.z;
  const int tbase = split * 512;
  int f = blockIdx.x + (blockIdx.y << 3);
  f = (f & 7) * 64 + (f >> 3);                 // XCD swizzle over 512 per split
  const int bh = f >> 3, b = bh >> 3, h = bh & 7;
  const int q0 = (f & 7) * 128;
  const int tid = threadIdx.x, w = tid >> 6, lane = tid & 63;
  const int l31 = lane & 31, hi2 = lane >> 5, sw = l31 & 7;
  const int qrow = q0 + w * 32 + l31;
  const short* __restrict__ qbase = Qb + (size_t)(b * 1024 + qrow) * 1024 + h * 128;
  s16x8 qf[8];
#pragma unroll
  for (int kc = 0; kc < 8; kc++) qf[kc] = *(const s16x8*)&qbase[kc * 16 + hi2 * 8];
  float lsum = 0.f;
  f32x16 acc[4];
#pragma unroll
  for (int db = 0; db < 4; db++)
#pragma unroll
    for (int r = 0; r < 16; r++) acc[db][r] = 0.f;
  const float sc2 = (float)(0.08838834764831845 * 1.4426950408889634);
  const int krow_ = tid >> 4, kslot = tid & 15;
  const int vrow_ = tid >> 3, vslot = tid & 7;
  const int vks = vslot >> 1, vm = vslot & 1;
  const short* __restrict__ Kg = Kb + (size_t)(b * 1024) * 1024 + h * 128;
  const short* __restrict__ Vg = Vt + (size_t)bh * 128 * 1024;
  const short* __restrict__ Bg = B2 + (size_t)(h * 1024 + qrow) * 1024;

  s16x8 krA[4], vrA[4], krB[4], vrB[4];
#define LOADT(KR, VR, T0)                                                              \
  do {                                                                                 \
    _Pragma("unroll")                                                                  \
    for (int i = 0; i < 4; i++)                                                        \
      KR[i] = *(const s16x8*)&Kg[(size_t)((T0) + i * 16 + krow_) * 1024 + kslot * 8];  \
    _Pragma("unroll")                                                                  \
    for (int i = 0; i < 4; i++)                                                        \
      VR[i] = *(const s16x8*)&Vg[(size_t)(i * 32 + vrow_) * 1024 + (T0) + vslot * 8];  \
  } while (0)

#define STAGE(KR, VR)                                                                  \
  do {                                                                                 \
    _Pragma("unroll")                                                                  \
    for (int i = 0; i < 4; i++) {                                                      \
      int row = i * 16 + krow_;                                                        \
      *(s16x8*)((char*)Kl + row * 256 + ((kslot ^ (row & 7)) << 4)) = KR[i];           \
    }                                                                                  \
    _Pragma("unroll")                                                                  \
    for (int i = 0; i < 4; i++) {                                                      \
      int row = i * 32 + vrow_;                                                        \
      char* vb = (char*)Vl + row * 128;                                                \
      s16x4 lo, hi4;                                                                   \
      lo[0] = VR[i][0]; lo[1] = VR[i][1]; lo[2] = VR[i][2]; lo[3] = VR[i][3];          \
      hi4[0] = VR[i][4]; hi4[1] = VR[i][5]; hi4[2] = VR[i][6]; hi4[3] = VR[i][7];      \
      *(s16x4*)(vb + (((vks * 2) ^ (row & 7)) << 4) + vm * 8) = lo;                    \
      *(s16x4*)(vb + (((vks * 2 + 1) ^ (row & 7)) << 4) + vm * 8) = hi4;               \
    }                                                                                  \
  } while (0)

#define COMPUTE(T0)                                                                    \
  do {                                                                                 \
    s16x4 br[8];                                                                       \
    _Pragma("unroll")                                                                  \
    for (int tb = 0; tb < 2; tb++)                                                     \
      _Pragma("unroll")                                                                \
      for (int u = 0; u < 4; u++)                                                      \
        br[tb * 4 + u] = *(const s16x4*)&Bg[(T0) + tb * 32 + u * 8 + 4 * hi2];         \
    f32x16 st[2];                                                                      \
    __builtin_amdgcn_s_setprio(1);                                                     \
    _Pragma("unroll")                                                                  \
    for (int tb = 0; tb < 2; tb++) {                                                   \
      _Pragma("unroll")                                                                \
      for (int r = 0; r < 16; r++) st[tb][r] = 0.f;                                    \
      _Pragma("unroll")                                                                \
      for (int kc = 0; kc < 8; kc++) {                                                 \
        s16x8 kf = *(const s16x8*)((const char*)Kl + (tb * 32 + l31) * 256 +           \
                                   (((kc * 2 + hi2) ^ sw) << 4));                      \
        st[tb] = mfma32(kf, qf[kc], st[tb]);                                           \
      }                                                                                \
    }                                                                                  \
    __builtin_amdgcn_s_setprio(0);                                                     \
    _Pragma("unroll")                                                                  \
    for (int tb = 0; tb < 2; tb++)                                                     \
      _Pragma("unroll")                                                                \
      for (int r = 0; r < 16; r++) {                                                   \
        float e = exp2f(fmaf(st[tb][r], sc2, bf2f(br[tb * 4 + (r >> 2)][r & 3])));     \
        st[tb][r] = e;                                                                 \
        lsum += e;                                                                     \
      }                                                                                \
    s16x8 pf[4];                                                                       \
    _Pragma("unroll")                                                                  \
    for (int ks = 0; ks < 4; ks++)                                                     \
      _Pragma("unroll")                                                                \
      for (int e = 0; e < 8; e++)                                                      \
        pf[ks][e] = f2bf(st[ks >> 1][(e & 3) + 8 * (ks & 1) + 4 * (e >> 2)]);          \
    __builtin_amdgcn_s_setprio(1);                                                     \
    _Pragma("unroll")                                                                  \
    for (int db = 0; db < 4; db++)                                                     \
      _Pragma("unroll")                                                                \
      for (int ks = 0; ks < 4; ks++) {                                                 \
        s16x8 vf = *(const s16x8*)((const char*)Vl + (db * 32 + l31) * 128 +           \
                                   (((ks * 2 + hi2) ^ sw) << 4));                      \
        acc[db] = mfma32(vf, pf[ks], acc[db]);                                         \
      }                                                                                \
    __builtin_amdgcn_s_setprio(0);                                                     \
  } while (0)

  LOADT(krA, vrA, tbase);
  for (int ih = 0; ih < 4; ++ih) {
    const int t0 = tbase + ih * 128;
    ASM_VMCNT0; SFENCE;
    STAGE(krA, vrA);
    LOADT(krB, vrB, t0 + 64);
    ASM_LGKM0; SFENCE; BARRIER; SFENCE;
    COMPUTE(t0);
    BARRIER; SFENCE;
    ASM_VMCNT0; SFENCE;
    STAGE(krB, vrB);
    if (ih < 3) LOADT(krA, vrA, t0 + 128);
    ASM_LGKM0; SFENCE; BARRIER; SFENCE;
    COMPUTE(t0 + 64);
    BARRIER; SFENCE;
  }
  // partial lsum over this split's t-range (lanes 32 apart disjoint slices)
  lsum += __shfl_xor(lsum, 32);
  if (lane < 32) Ls[split * 65536 + bh * 1024 + qrow] = lsum;
  __syncthreads();
  // epilogue: UNNORMALIZED O-partial via swizzled LDS bounce [128 q][128 d]
  short* Ol = lds;
  const int qloc = w * 32 + l31, qs = qloc & 7;
#pragma unroll
  for (int db = 0; db < 4; db++) {
#pragma unroll
    for (int u = 0; u < 4; u++) {
      int d0 = db * 32 + u * 8 + 4 * hi2;
      s16x4 v;
      v[0] = f2bf(acc[db][4 * u + 0]);
      v[1] = f2bf(acc[db][4 * u + 1]);
      v[2] = f2bf(acc[db][4 * u + 2]);
      v[3] = f2bf(acc[db][4 * u + 3]);
      *(s16x4*)((char*)Ol + qloc * 256 + (((d0 >> 3) ^ qs) << 4) + (d0 & 7) * 2) = v;
    }
  }
  __syncthreads();
  short* Od = Op + (size_t)split * 8388608;
#pragma unroll
  for (int it = 0; it < 8; ++it) {
    int idx = tid + it * 256;
    int row = idx >> 4, c = idx & 15;
    s16x8 vv = *(const s16x8*)((const char*)Ol + row * 256 + ((c ^ (row & 7)) << 4));
    *(s16x8*)&Od[(size_t)(b * 1024 + q0 + row) * 1024 + h * 128 + c * 8] = vv;
  }
#undef LOADT
#undef STAGE
#undef COMPUTE
}

// ---------------- merge partials: O = (O0 + O1) / (l0 + l1) -----------------
__global__ __launch_bounds__(256) void k_merge(const short* __restrict__ Op, const float* __restrict__ Ls,
                                               short* __restrict__ O) {
  for (int g = blockIdx.x * 256 + threadIdx.x; g < 2097152; g += 262144) {
    const int q_h = g >> 4;            // (b*1024+q)*8 + h
    const int h = q_h & 7;
    const int bq = q_h >> 3;
    const int b = bq >> 10, q = bq & 1023;
    const int li = (b * 8 + h) * 1024 + q;
    const float inv = 1.f / (Ls[li] + Ls[65536 + li]);
    s16x8 p0 = ((const s16x8*)Op)[g];
    s16x8 p1 = ((const s16x8*)(Op + 8388608))[g];
    s16x8 o;
#pragma unroll
    for (int e = 0; e < 8; e++) o[e] = f2bf((bf2f(p0[e]) + bf2f(p1[e])) * inv);
    ((s16x8*)O)[g] = o;
  }
}

// ---------------- O-proj GEMM + fused mp_sum residual (fp32 out) ------------
__global__ __launch_bounds__(256) void k_gemm_o(const short* __restrict__ X, const short* __restrict__ Wm,
                                                const float* __restrict__ Qin, float* __restrict__ Out) {
  __shared__ short lds[16384];
  short* Al = lds;
  short* Bl = lds + 8192;
  const int m0 = blockIdx.x * 128, n0 = blockIdx.y * 128;
  const int tid = threadIdx.x, lane = tid & 63, w = tid >> 6;
  const int hi = lane >> 4, ql = lane & 15;
  const int wm = w >> 1, wn_ = w & 1;
  f32x4 acc[4][4];
#pragma unroll
  for (int i = 0; i < 4; i++)
#pragma unroll
    for (int j = 0; j < 4; j++) acc[i][j] = (f32x4){0.f, 0.f, 0.f, 0.f};
  gemm_core(X, Wm, m0, n0, lane, w, hi, ql, wm, wn_, Al, Bl, acc);
#pragma unroll
  for (int i = 0; i < 4; i++) {
    int mg = m0 + wm * 64 + i * 16 + 4 * hi;
#pragma unroll
    for (int j = 0; j < 4; j++) {
      int ng = n0 + wn_ * 64 + j * 16 + ql;
#pragma unroll
      for (int r = 0; r < 4; r++) {
        size_t idx = (size_t)(mg + r) * 1024 + ng;
        Out[idx] = (Qin[idx] + acc[i][j][r]) * 0.7071067811865476f;
      }
    }
  }
}

extern "C" void kernel_launch(void* const* d_in, const int* in_sizes, int n_in,
                              void* d_out, int out_size, void* d_ws, size_t ws_size,
                              hipStream_t stream) {
  (void)in_sizes; (void)n_in; (void)out_size; (void)ws_size;
  const float* query = (const float*)d_in[0];
  const float* gain_s = (const float*)d_in[1];
  // d_in[2] = gain_t (unused: time_dim=0)
  const float* qw = (const float*)d_in[3];
  const float* kw = (const float*)d_in[4];
  const float* vw = (const float*)d_in[5];
  const float* ow = (const float*)d_in[6];
  const float* bias = (const float*)d_in[7];
  float* out = (float*)d_out;

  // workspace: 60M shorts (120 MB) + 512 KB lsum
  short* ws = (short*)d_ws;
  short* s_wn = ws;                       // 4 x 1M  (q,k,v,o normalized bf16)
  short* s_x  = s_wn + 4 * 1048576;       // 8M  query bf16; REUSED as merged O
  short* s_B2 = s_x + 8388608;            // 8M  bf16 bias * log2e
  short* s_Q  = s_B2 + 8388608;           // 8M
  short* s_K  = s_Q + 8388608;            // 8M
  short* s_Vt = s_K + 8388608;            // 8M  V transposed [b][h][d][s]
  short* s_Op = s_Vt + 8388608;           // 16M bf16 O-partials (2 splits)
  float* s_Ls = (float*)(s_Op + 16777216); // 128K f32 lsum partials
  short* s_O  = s_x;                      // alias: x dead after QKV GEMM

  k_prep<<<dim3(8192), dim3(256), 0, stream>>>(qw, kw, vw, ow, gain_s, query, bias, s_wn, s_x, s_B2);
  k_gemm_qkv<<<dim3(64, 8, 3), dim3(256), 0, stream>>>(s_x, s_wn, s_Q, s_K, s_Vt);
  k_attn<<<dim3(8, 64, 2), dim3(256), 0, stream>>>(s_Q, s_K, s_Vt, s_B2, s_Op, s_Ls);
  k_merge<<<dim3(1024), dim3(256), 0, stream>>>(s_Op, s_Ls, s_O);
  k_gemm_o<<<dim3(64, 8), dim3(256), 0, stream>>>(s_O, s_wn + 3 * 1048576, query, out);
}